// Round 3
// baseline (243.766 us; speedup 1.0000x reference)
//
#include <hip/hip_runtime.h>
#include <math.h>

// ---------------------------------------------------------------------------
// RecursiveEncoder forward, fp16 MFMA pipeline. Round 6:
//  - k1 lA k-slot ROTATION swizzle: phys_slot = (ks + 2*(row>>3)) & 31 for
//    k<256 (one-hot region identity). Kills the 3-way bank conflict on the
//    leaf C-scatter (5.9M conflict cycles) while keeping b128 reads uniform.
//  - box pre-converted to f16 fragment rows [NPAR*10][16] by kconv; leaf
//    MFMA switched to 16x16x16 (K=16>=10): coalesced f16x4 frags, zero
//    pack VALU, no divergent float2 gathers.
//  - occupancy: k1 launch_bounds(256,3) (3 blocks/CU, LDS 158KB), k2 (256,4).
// ---------------------------------------------------------------------------

#define NPAR  32768
#define LDA1  328        // k1 activation row (halfs): K=320 + 8 pad
#define LDA2  264        // xbuf row (halfs): K=256 + 8 pad
// ws layout (halfs):
#define W1F_OFF   0                  // frag-order W1^T: ((n16*10+c)*64+lane)*8
#define W2F_OFF   81920              // 4 x frag-order [((n16*8+c)*64+lane)*8]
#define WBX_OFF   (81920 + 4*65536)  // frag-order Wbox^T (16x16x16): ((n16*64+lane))*4
#define XBUF_OFF  (WBX_OFF + 8192)   // = 352256; [NPAR][264]
#define BOXF_OFF  (XBUF_OFF + NPAR*264)  // = 9003008; [NPAR*10][16] f16

typedef _Float16 f16;
typedef _Float16 f16x8 __attribute__((ext_vector_type(8)));
typedef _Float16 f16x4 __attribute__((ext_vector_type(4)));
typedef float    f32x4 __attribute__((ext_vector_type(4)));

__device__ __forceinline__ void async16(const void* g, void* l) {
    __builtin_amdgcn_global_load_lds((const __attribute__((address_space(1))) void*)g,
                                     (__attribute__((address_space(3))) void*)l, 16, 0, 0);
}
__device__ __forceinline__ f32x4 mfma16(f16x8 a, f16x8 b, f32x4 c) {
    return __builtin_amdgcn_mfma_f32_16x16x32_f16(a, b, c, 0, 0, 0);
}
__device__ __forceinline__ f32x4 mfma16k(f16x4 a, f16x4 b, f32x4 c) {
    return __builtin_amdgcn_mfma_f32_16x16x16f16(a, b, c, 0, 0, 0);
}

// ---------------- kconv: fragment-ordered f16 weights + box f16 rows ---------
// Fragment layout (K=32 chunks): for col-tile n16, k-chunk c, lane=q*16+r16
// holds halfs j=0..7 of W^T[n16*16+r16][c*32+q*8+j].
// WboxF (16x16x16, K=16): lane holds j=0..3 of W^T[n16*16+r16][q*4+j].
__global__ void kconv(const float* __restrict__ W1, const float* __restrict__ W2,
                      const float* __restrict__ Ws1, const float* __restrict__ Wmu,
                      const float* __restrict__ Wvar, const float* __restrict__ Wbox,
                      const float* __restrict__ box, f16* __restrict__ ws) {
    int idx = blockIdx.x * 256 + threadIdx.x;
    if (idx < 81920) {                       // W1F (K=320: 10 chunks)
        int j = idx & 7, lane = (idx >> 3) & 63, t = idx >> 9;   // t = n16*10+c
        int c = t % 10, n16 = t / 10;
        int k = c * 32 + (lane >> 4) * 8 + j;
        int n = n16 * 16 + (lane & 15);
        ws[idx] = (f16)W1[k * 256 + n];
    } else if (idx < WBX_OFF) {              // W2/Ws1/Wmu/Wvar (K=256: 8 chunks)
        int r = idx - 81920;
        int wsel = r >> 16, r2 = r & 65535;
        const float* s = (wsel == 0) ? W2 : (wsel == 1) ? Ws1 : (wsel == 2) ? Wmu : Wvar;
        int j = r2 & 7, lane = (r2 >> 3) & 63, c = (r2 >> 9) & 7, n16 = r2 >> 12;
        int k = c * 32 + (lane >> 4) * 8 + j;
        int n = n16 * 16 + (lane & 15);
        ws[idx] = (f16)s[k * 256 + n];
    } else if (idx < WBX_OFF + 4096) {       // WboxF (16x16x16 frags, K=16 pad)
        int r = idx - WBX_OFF;
        int j = r & 3, lane = (r >> 2) & 63, n16 = r >> 8;
        int k = (lane >> 4) * 4 + j;
        int n = n16 * 16 + (lane & 15);
        ws[idx] = (f16)((k < 10) ? Wbox[k * 256 + n] : 0.f);
    } else if (idx >= XBUF_OFF) {            // box rows f32[10] -> f16[16]
        int row = idx - XBUF_OFF;
        if (row < NPAR * 10) {
            const float* bp = box + (size_t)row * 10;
            float2 v0 = *(const float2*)(bp + 0), v1 = *(const float2*)(bp + 2);
            float2 v2 = *(const float2*)(bp + 4), v3 = *(const float2*)(bp + 6);
            float2 v4 = *(const float2*)(bp + 8);
            f16x8 lo, hi;
            lo[0] = (f16)v0.x; lo[1] = (f16)v0.y; lo[2] = (f16)v1.x; lo[3] = (f16)v1.y;
            lo[4] = (f16)v2.x; lo[5] = (f16)v2.y; lo[6] = (f16)v3.x; lo[7] = (f16)v3.y;
            hi[0] = (f16)v4.x; hi[1] = (f16)v4.y;
            hi[2] = (f16)0.f; hi[3] = (f16)0.f; hi[4] = (f16)0.f;
            hi[5] = (f16)0.f; hi[6] = (f16)0.f; hi[7] = (f16)0.f;
            f16* dst = ws + BOXF_OFF + (size_t)row * 16;
            *(f16x8*)dst = lo;
            *(f16x8*)(dst + 8) = hi;
        }
    }
}
#define KCONV_THREADS (XBUF_OFF + NPAR*10)   // 679936 = 2656 * 256

// ---------------- k1: leaf MFMA + K=320 GEMM (one-hot fused) + reg max-pool --
// block = 8 parents = 80 rows; grid 4096; 256 thr (4 waves, each N=64)
// Row PERMUTATION: child (p,m) lives at lA row d = m*8 + p. Then C row
// mt*16+q*4+i has p = i+4*(q&1), m = 2*mt+(q>>1)  (all compile-time indices).
// lA k-slot swizzle (16B slots): phys = (ks + 2*(row>>3)) & 31 for ks<32,
// identity for ks 32..39 (one-hot). Bijective per row; store groups land on
// 8 distinct bank-groups; b128 reads stay uniform (8 lanes/group).
__global__ __launch_bounds__(256, 3)
void k1(const f16* __restrict__ boxf, const float* __restrict__ bbox,
        const float* __restrict__ b1, const int* __restrict__ sem,
        const int* __restrict__ nch, const f16* __restrict__ wsh,
        f16* __restrict__ xbuf) {
    __shared__ __align__(16) f16 lA[80 * LDA1];   // 52480 B
    __shared__ int lnc[8];

    int tid = threadIdx.x, blk = blockIdx.x;
    int w = tid >> 6, lane = tid & 63, q = lane >> 4, r16 = lane & 15;
    int r3 = r16 >> 3, r7 = r16 & 7;
    const f16* w1f = wsh + W1F_OFF;
    const f16* wbxf = wsh + WBX_OFF;

    if (tid < 8) lnc[tid] = nch[blk * 8 + tid];

    float bbv[4], b1v[4];
    #pragma unroll
    for (int nt = 0; nt < 4; nt++) {
        int col = w * 64 + nt * 16 + r16;
        bbv[nt] = bbox[col];
        b1v[nt] = b1[col];
    }

    // ---- leaf: relu(box @ Wbox + bbox), 16x16x16, frags fully coalesced
    f32x4 acc[5][4];
    {
        f16x4 bb4[4], ab4[5];
        #pragma unroll
        for (int nt = 0; nt < 4; nt++)
            bb4[nt] = *(const f16x4*)&wbxf[((w * 4 + nt) * 64 + lane) * 4];
        #pragma unroll
        for (int mt = 0; mt < 5; mt++)
            ab4[mt] = *(const f16x4*)&boxf[((size_t)blk * 80 + mt * 16 + r16) * 16 + q * 4];
        #pragma unroll
        for (int mt = 0; mt < 5; mt++)
            #pragma unroll
            for (int nt = 0; nt < 4; nt++)
                acc[mt][nt] = mfma16k(ab4[mt], bb4[nt], (f32x4){0.f, 0.f, 0.f, 0.f});
    }
    // leaf -> lA (C-layout scatter, PERMUTED rows d = m*8+p, swizzled slots)
    #pragma unroll
    for (int mt = 0; mt < 5; mt++) {
        #pragma unroll
        for (int i = 0; i < 4; i++) {
            int r = mt * 16 + q * 4 + i;        // original child row 0..79
            int p = (r * 205) >> 11;            // r / 10 (exact for r<80)
            int m = r - 10 * p;
            int dbase = (m * 8 + p) * LDA1;     // permuted row base
            #pragma unroll
            for (int nt = 0; nt < 4; nt++) {
                int ks = w * 8 + nt * 2 + r3;   // 16B slot of col
                int sp = (ks + 2 * m) & 31;     // rotation by 2*(row>>3)=2m
                lA[dbase + sp * 8 + r7] = (f16)fmaxf(acc[mt][nt][i] + bbv[nt], 0.f);
            }
        }
    }
    // one-hot region k=256..319 (slots 32..39, identity): tid IS permuted row d
    if (tid < 80) {
        int p8 = tid & 7, m8 = tid >> 3;
        int sid = sem[blk * 80 + p8 * 10 + m8];
        f16x8 z = {(f16)0.f, (f16)0.f, (f16)0.f, (f16)0.f, (f16)0.f, (f16)0.f, (f16)0.f, (f16)0.f};
        #pragma unroll
        for (int j = 0; j < 8; j++) *(f16x8*)&lA[tid * LDA1 + 256 + j * 8] = z;
        lA[tid * LDA1 + 256 + sid] = (f16)1.f;
    }

    // ---- main GEMM: K=320, coalesced frag stream, 3-deep pipeline
    #pragma unroll
    for (int mt = 0; mt < 5; mt++)
        #pragma unroll
        for (int nt = 0; nt < 4; nt++) acc[mt][nt] = (f32x4){0.f, 0.f, 0.f, 0.f};

    f16x8 bs[3][4];
    auto loadB = [&](int c, int s) {
        #pragma unroll
        for (int nt = 0; nt < 4; nt++)
            bs[s][nt] = *(const f16x8*)&w1f[(((w * 4 + nt) * 10 + c) * 64 + lane) * 8];
    };
    loadB(0, 0); loadB(1, 1); loadB(2, 2);
    __syncthreads();                               // lA (leaf + one-hot) visible
    #pragma unroll
    for (int c = 0; c < 10; c++) {
        f16x8 a[5];
        #pragma unroll
        for (int mt = 0; mt < 5; mt++) {
            int ks = 4 * c + q;
            int sp = (c < 8) ? ((ks + 4 * mt + 2 * r3) & 31) : ks;  // 2*(row>>3)
            a[mt] = *(const f16x8*)&lA[(mt * 16 + r16) * LDA1 + sp * 8];
        }
        int s = c % 3;
        #pragma unroll
        for (int mt = 0; mt < 5; mt++)
            #pragma unroll
            for (int nt = 0; nt < 4; nt++) acc[mt][nt] = mfma16(a[mt], bs[s][nt], acc[mt][nt]);
        if (c + 3 < 10) loadB(c + 3, s);
    }
    // NO barrier: lA never rewritten; epilogue is all in registers.

    // ---- in-register masked max-pool over children
    int qh = q >> 1, qb = q & 1;
    int ncv[4];
    #pragma unroll
    for (int i = 0; i < 4; i++) ncv[i] = lnc[4 * qb + i];   // parent p = i + 4*qb
    float pm[4][4];
    #pragma unroll
    for (int i = 0; i < 4; i++)
        #pragma unroll
        for (int nt = 0; nt < 4; nt++) pm[i][nt] = 0.f;
    #pragma unroll
    for (int mt = 0; mt < 5; mt++) {
        int m = 2 * mt + qh;                                 // child index
        #pragma unroll
        for (int i = 0; i < 4; i++) {
            bool live = m < ncv[i];
            #pragma unroll
            for (int nt = 0; nt < 4; nt++) {
                float v = fmaxf(acc[mt][nt][i] + b1v[nt], 0.f);
                pm[i][nt] = fmaxf(pm[i][nt], live ? v : 0.f);
            }
        }
    }
    // combine even-m partials (q=0,1) with odd-m partials (q=2,3): lane ^ 32
    #pragma unroll
    for (int i = 0; i < 4; i++)
        #pragma unroll
        for (int nt = 0; nt < 4; nt++)
            pm[i][nt] = fmaxf(pm[i][nt], __shfl_xor(pm[i][nt], 32, 64));
    // q=0 writes parents 0..3, q=1 writes parents 4..7 (q=2,3 hold duplicates)
    if (q < 2) {
        #pragma unroll
        for (int i = 0; i < 4; i++) {
            size_t row = (size_t)blk * 8 + 4 * q + i;
            #pragma unroll
            for (int nt = 0; nt < 4; nt++)
                xbuf[row * LDA2 + w * 64 + nt * 16 + r16] = (f16)pm[i][nt];
        }
    }
}

// ---------------- k2: sampler chain, M=32/block, coalesced frag streams ------
// grid 1024; 256 thr; LDS = 2 x 16896 B -> 4 blocks/CU
__global__ __launch_bounds__(256, 4)
void k2(const f16* __restrict__ xbuf, const f16* __restrict__ wsh,
        const float* __restrict__ b2, const float* __restrict__ bs1,
        const float* __restrict__ bmu, const float* __restrict__ bvar,
        const float* __restrict__ eps, float* __restrict__ out) {
    __shared__ __align__(16) f16 actA[32 * LDA2];
    __shared__ __align__(16) f16 actB[32 * LDA2];

    int tid = threadIdx.x, blk = blockIdx.x;
    int w = tid >> 6, lane = tid & 63, q = lane >> 4, r16 = lane & 15;
    const f16* w2f   = wsh + W2F_OFF;
    const f16* ws1f  = w2f + 65536;
    const f16* wmuf  = w2f + 2 * 65536;
    const f16* wvarf = w2f + 3 * 65536;

    float b2v[4], bs1v[4], bmv[4], bvv[4];
    #pragma unroll
    for (int nt = 0; nt < 4; nt++) {
        int col = w * 64 + nt * 16 + r16;
        b2v[nt] = b2[col]; bs1v[nt] = bs1[col];
        bmv[nt] = bmu[col]; bvv[nt] = bvar[col];
    }

    {   // stage x tile (16896 B flat) -> actA
        const char* src = (const char*)(xbuf + (size_t)blk * 32 * LDA2);
        #pragma unroll
        for (int j = 0; j < 5; j++) {
            int idx = tid + j * 256;
            if (idx < 1056) async16(src + idx * 16, (char*)actA + idx * 16);
        }
    }

    f32x4 acc[2][4];
    f16x8 bs[3][4];
    auto loadB = [&](const f16* wt, int c, int s) {
        #pragma unroll
        for (int nt = 0; nt < 4; nt++)
            bs[s][nt] = *(const f16x8*)&wt[(((w * 4 + nt) * 8 + c) * 64 + lane) * 8];
    };
    auto gemm = [&](const f16* A, const f16* wt) {   // caller preloads bs[0..2]
        #pragma unroll
        for (int mt = 0; mt < 2; mt++)
            #pragma unroll
            for (int nt = 0; nt < 4; nt++) acc[mt][nt] = (f32x4){0.f, 0.f, 0.f, 0.f};
        #pragma unroll
        for (int c = 0; c < 8; c++) {
            f16x8 a[2];
            #pragma unroll
            for (int mt = 0; mt < 2; mt++)
                a[mt] = *(const f16x8*)&A[(mt * 16 + r16) * LDA2 + c * 32 + q * 8];
            int s = c % 3;
            #pragma unroll
            for (int mt = 0; mt < 2; mt++)
                #pragma unroll
                for (int nt = 0; nt < 4; nt++) acc[mt][nt] = mfma16(a[mt], bs[s][nt], acc[mt][nt]);
            if (c + 3 < 8) loadB(wt, c + 3, s);
        }
    };

    // stage1: parent = relu(x @ W2 + b2) -> actB
    loadB(w2f, 0, 0); loadB(w2f, 1, 1); loadB(w2f, 2, 2);
    __syncthreads();                               // drains actA staging
    gemm(actA, w2f);
    #pragma unroll
    for (int nt = 0; nt < 4; nt++) {
        int col = w * 64 + nt * 16 + r16;
        #pragma unroll
        for (int mt = 0; mt < 2; mt++)
            #pragma unroll
            for (int i = 0; i < 4; i++)
                actB[(mt * 16 + q * 4 + i) * LDA2 + col] = (f16)fmaxf(acc[mt][nt][i] + b2v[nt], 0.f);
    }
    loadB(ws1f, 0, 0); loadB(ws1f, 1, 1); loadB(ws1f, 2, 2);
    __syncthreads();

    // stage2: enc = relu(parent @ Ws1 + bs1) -> actA
    gemm(actB, ws1f);
    #pragma unroll
    for (int nt = 0; nt < 4; nt++) {
        int col = w * 64 + nt * 16 + r16;
        #pragma unroll
        for (int mt = 0; mt < 2; mt++)
            #pragma unroll
            for (int i = 0; i < 4; i++)
                actA[(mt * 16 + q * 4 + i) * LDA2 + col] = (f16)fmaxf(acc[mt][nt][i] + bs1v[nt], 0.f);
    }
    loadB(wmuf, 0, 0); loadB(wmuf, 1, 1); loadB(wmuf, 2, 2);
    __syncthreads();

    // stage3: mu -> regs
    gemm(actA, wmuf);
    f32x4 mu[2][4];
    #pragma unroll
    for (int mt = 0; mt < 2; mt++)
        #pragma unroll
        for (int nt = 0; nt < 4; nt++) mu[mt][nt] = acc[mt][nt];

    // prefetch eps while stage4 runs
    float ev[2][4][4];
    #pragma unroll
    for (int mt = 0; mt < 2; mt++)
        #pragma unroll
        for (int i = 0; i < 4; i++) {
            size_t grow = (size_t)blk * 32 + mt * 16 + q * 4 + i;
            #pragma unroll
            for (int nt = 0; nt < 4; nt++)
                ev[mt][nt][i] = eps[grow * 256 + w * 64 + nt * 16 + r16];
        }

    // stage4: logvar + fused sampler epilogue (actA unchanged: no barrier)
    loadB(wvarf, 0, 0); loadB(wvarf, 1, 1); loadB(wvarf, 2, 2);
    gemm(actA, wvarf);
    #pragma unroll
    for (int mt = 0; mt < 2; mt++)
        #pragma unroll
        for (int nt = 0; nt < 4; nt++) {
            int col = w * 64 + nt * 16 + r16;
            #pragma unroll
            for (int i = 0; i < 4; i++) {
                size_t grow = (size_t)blk * 32 + mt * 16 + q * 4 + i;
                float m_ = mu[mt][nt][i] + bmv[nt];
                float lv = acc[mt][nt][i] + bvv[nt];
                float e  = expf(lv);
                out[grow * 512 + col]       = ev[mt][nt][i] * sqrtf(e) + m_;
                out[grow * 512 + 256 + col] = 1.f + lv - m_ * m_ - e;
            }
        }
}

// ---------------------------------------------------------------------------
extern "C" void kernel_launch(void* const* d_in, const int* in_sizes, int n_in,
                              void* d_out, int out_size, void* d_ws, size_t ws_size,
                              hipStream_t stream) {
    const float* box  = (const float*)d_in[0];
    const float* eps  = (const float*)d_in[1];
    const float* Wbox = (const float*)d_in[2];
    const float* bbox = (const float*)d_in[3];
    const float* W1   = (const float*)d_in[4];
    const float* b1   = (const float*)d_in[5];
    const float* W2   = (const float*)d_in[6];
    const float* b2   = (const float*)d_in[7];
    const float* Ws1  = (const float*)d_in[8];
    const float* bs1  = (const float*)d_in[9];
    const float* Wmu  = (const float*)d_in[10];
    const float* bmu  = (const float*)d_in[11];
    const float* Wvar = (const float*)d_in[12];
    const float* bvar = (const float*)d_in[13];
    const int*   sem  = (const int*)d_in[14];
    const int*   nch  = (const int*)d_in[15];

    f16* wsh  = (f16*)d_ws;
    f16* xbuf = wsh + XBUF_OFF;
    f16* boxf = wsh + BOXF_OFF;

    kconv<<<KCONV_THREADS / 256, 256, 0, stream>>>(W1, W2, Ws1, Wmu, Wvar, Wbox, box, wsh);
    k1<<<NPAR / 8, 256, 0, stream>>>(boxf, bbox, b1, sem, nch, wsh, xbuf);
    k2<<<NPAR / 32, 256, 0, stream>>>(xbuf, wsh, b2, bs1, bmu, bvar, eps, (float*)d_out);
}